// Round 2
// baseline (3248.631 us; speedup 1.0000x reference)
//
#include <hip/hip_runtime.h>
#include <cfloat>
#include <climits>

// VectorQuantizer2: z [32,2048,256] fp32, codebook [4096,256] fp32.
#define D     256
#define NE    4096
#define MT    128      // rows per block tile
#define KT    128      // codes per k-tile
#define DK    32       // d-chunk staged through LDS
#define LDSP  132      // padded LDS leading dim
// Candidate margin: covers np's fp32 rounding envelope 2Q <= ~6.3e-5
// (half-ulp(A+B) + half-ulp(score) each side, scores ~256) + fast-dot error.
#define DELTA     8e-5f
#define CAND_CAP  131072

// ---------------------------------------------------------------------------
// numpy-bit-exact fp32 helpers. __fmul_rn/__fadd_rn are contraction barriers.

// numpy pairwise_sum (scalar 8-accumulator block) of p[i]^2 over one 128-block.
__device__ __forceinline__ float np_block128_sq(const float* __restrict__ p) {
    float r[8];
    #pragma unroll
    for (int j = 0; j < 8; ++j) r[j] = __fmul_rn(p[j], p[j]);
    #pragma unroll
    for (int i = 8; i < 128; i += 8)
        #pragma unroll
        for (int j = 0; j < 8; ++j) r[j] = __fadd_rn(r[j], __fmul_rn(p[i + j], p[i + j]));
    return __fadd_rn(__fadd_rn(__fadd_rn(r[0], r[1]), __fadd_rn(r[2], r[3])),
                     __fadd_rn(__fadd_rn(r[4], r[5]), __fadd_rn(r[6], r[7])));
}
// np.sum(row**2) for 256 contiguous fp32: pairwise split 128+128.
__device__ __forceinline__ float np_sumsq256(const float* __restrict__ p) {
    return __fadd_rn(np_block128_sq(p), np_block128_sq(p + 128));
}

// np.einsum('nd,kd->nk', optimize=False) inner dot, baseline-SIMD emulation:
// SSE (4 lanes), no FMA, 16 elems/iter, chained muladd order p3,p2,p1,p0,
// final SSE3 hadd: (v0+v1)+(v2+v3).
__device__ __forceinline__ float np_einsum_dot256(const float* __restrict__ zr,
                                                  const float* __restrict__ er) {
    float v0 = 0.f, v1 = 0.f, v2 = 0.f, v3 = 0.f;
    for (int t = 0; t < 256; t += 16) {
        float4 a0 = *(const float4*)(zr + t);
        float4 a1 = *(const float4*)(zr + t + 4);
        float4 a2 = *(const float4*)(zr + t + 8);
        float4 a3 = *(const float4*)(zr + t + 12);
        float4 b0 = *(const float4*)(er + t);
        float4 b1 = *(const float4*)(er + t + 4);
        float4 b2 = *(const float4*)(er + t + 8);
        float4 b3 = *(const float4*)(er + t + 12);
        v0 = __fadd_rn(v0, __fmul_rn(a3.x, b3.x));
        v1 = __fadd_rn(v1, __fmul_rn(a3.y, b3.y));
        v2 = __fadd_rn(v2, __fmul_rn(a3.z, b3.z));
        v3 = __fadd_rn(v3, __fmul_rn(a3.w, b3.w));
        v0 = __fadd_rn(v0, __fmul_rn(a2.x, b2.x));
        v1 = __fadd_rn(v1, __fmul_rn(a2.y, b2.y));
        v2 = __fadd_rn(v2, __fmul_rn(a2.z, b2.z));
        v3 = __fadd_rn(v3, __fmul_rn(a2.w, b2.w));
        v0 = __fadd_rn(v0, __fmul_rn(a1.x, b1.x));
        v1 = __fadd_rn(v1, __fmul_rn(a1.y, b1.y));
        v2 = __fadd_rn(v2, __fmul_rn(a1.z, b1.z));
        v3 = __fadd_rn(v3, __fmul_rn(a1.w, b1.w));
        v0 = __fadd_rn(v0, __fmul_rn(a0.x, b0.x));
        v1 = __fadd_rn(v1, __fmul_rn(a0.y, b0.y));
        v2 = __fadd_rn(v2, __fmul_rn(a0.z, b0.z));
        v3 = __fadd_rn(v3, __fmul_rn(a0.w, b0.w));
    }
    return __fadd_rn(__fadd_rn(v0, v1), __fadd_rn(v2, v3));
}

// ---------------------------------------------------------------------------
// K1: Bnp[k] = np-exact sum(cb[k]**2)
__global__ void bnp_kernel(const float* __restrict__ cb, float* __restrict__ Bnp) {
    int k = blockIdx.x * 256 + threadIdx.x;
    if (k < NE) Bnp[k] = np_sumsq256(cb + (size_t)k * D);
}
// K2: Anp[r] = np-exact sum(z[r]**2)
__global__ void anp_kernel(const float* __restrict__ z, float* __restrict__ Anp) {
    int r = blockIdx.x * 256 + threadIdx.x;
    Anp[r] = np_sumsq256(z + (size_t)r * D);
}

// ---------------------------------------------------------------------------
// K3 (stage A): fast fp32 tiled GEMM, exact per-row top-2 of s~ = Bnp - 2*dot.
// Rows with top-2 gap <= DELTA are flagged for the np-exact path.
__global__ __launch_bounds__(256, 2)
void stageA(const float* __restrict__ z, const float* __restrict__ cb,
            const float* __restrict__ Bnp, int* __restrict__ idxArr,
            float* __restrict__ rowMin, unsigned long long* __restrict__ rowKey,
            int* __restrict__ flagCnt, int* __restrict__ flagList) {
    __shared__ float smem[2 * DK * LDSP];
    float (*zt)[LDSP] = (float (*)[LDSP])smem;
    float (*ct)[LDSP] = (float (*)[LDSP])(smem + DK * LDSP);

    const int tid = threadIdx.x;
    const int tx  = tid & 15;
    const int ty  = tid >> 4;
    const int R0  = blockIdx.x * MT;

    float best1[8], best2[8];
    int   bidx[8];
    #pragma unroll
    for (int i = 0; i < 8; ++i) { best1[i] = FLT_MAX; best2[i] = FLT_MAX; bidx[i] = 0; }

    for (int kt = 0; kt < NE; kt += KT) {
        float acc[8][8];
        #pragma unroll
        for (int i = 0; i < 8; ++i)
            #pragma unroll
            for (int j = 0; j < 8; ++j) acc[i][j] = 0.f;

        for (int d0 = 0; d0 < D; d0 += DK) {
            __syncthreads();
            #pragma unroll
            for (int it = 0; it < 4; ++it) {
                int q  = tid + 256 * it;
                int r  = q >> 3;
                int dd = (q & 7) << 2;
                float4 zv = *(const float4*)(z  + (size_t)(R0 + r) * D + d0 + dd);
                float4 cv = *(const float4*)(cb + (size_t)(kt + r) * D + d0 + dd);
                zt[dd + 0][r] = zv.x; zt[dd + 1][r] = zv.y;
                zt[dd + 2][r] = zv.z; zt[dd + 3][r] = zv.w;
                ct[dd + 0][r] = cv.x; ct[dd + 1][r] = cv.y;
                ct[dd + 2][r] = cv.z; ct[dd + 3][r] = cv.w;
            }
            __syncthreads();
            #pragma unroll 4
            for (int dd = 0; dd < DK; ++dd) {
                float4 za = *(const float4*)&zt[dd][ty * 8];
                float4 zb = *(const float4*)&zt[dd][ty * 8 + 4];
                float4 ca = *(const float4*)&ct[dd][tx * 8];
                float4 cc = *(const float4*)&ct[dd][tx * 8 + 4];
                float zf[8] = {za.x, za.y, za.z, za.w, zb.x, zb.y, zb.z, zb.w};
                float cf[8] = {ca.x, ca.y, ca.z, ca.w, cc.x, cc.y, cc.z, cc.w};
                #pragma unroll
                for (int i = 0; i < 8; ++i)
                    #pragma unroll
                    for (int j = 0; j < 8; ++j)
                        acc[i][j] = fmaf(zf[i], cf[j], acc[i][j]);
            }
        }
        const int cbase = kt + tx * 8;
        float4 ea = *(const float4*)(Bnp + cbase);
        float4 eb = *(const float4*)(Bnp + cbase + 4);
        float e2v[8] = {ea.x, ea.y, ea.z, ea.w, eb.x, eb.y, eb.z, eb.w};
        #pragma unroll
        for (int i = 0; i < 8; ++i) {
            #pragma unroll
            for (int j = 0; j < 8; ++j) {
                float s = fmaf(-2.f, acc[i][j], e2v[j]);
                if (s < best1[i]) { best2[i] = best1[i]; best1[i] = s; bidx[i] = cbase + j; }
                else if (s < best2[i]) best2[i] = s;
            }
        }
    }

    __syncthreads();
    float* rb1 = smem;
    float* rb2 = smem + MT * 16;
    int*   rix = (int*)(smem + 2 * MT * 16);
    #pragma unroll
    for (int i = 0; i < 8; ++i) {
        int r = ty * 8 + i;
        rb1[r * 16 + tx] = best1[i];
        rb2[r * 16 + tx] = best2[i];
        rix[r * 16 + tx] = bidx[i];
    }
    __syncthreads();
    if (tid < MT) {
        int r = tid;
        float b1 = FLT_MAX, b2 = FLT_MAX; int ix = INT_MAX;
        for (int t = 0; t < 16; ++t) {
            float e1 = rb1[r * 16 + t];
            float es = rb2[r * 16 + t];
            int   i1 = rix[r * 16 + t];
            if (e1 < b1 || (e1 == b1 && i1 < ix)) {
                b2 = fminf(b1, es);
                b1 = e1; ix = i1;
            } else {
                b2 = fminf(b2, e1);
            }
        }
        idxArr[R0 + r] = ix;
        rowMin[R0 + r] = b1;
        rowKey[R0 + r] = ~0ULL;
        if (b2 - b1 <= DELTA) {
            int p = atomicAdd(flagCnt, 1);
            flagList[p] = R0 + r;
        }
    }
}

// ---------------------------------------------------------------------------
// K4 (stage B): for flagged rows, tiled rescan of ALL codes; every code with
// s~ <= rowMin + DELTA is appended as an (row,code) candidate.
__global__ __launch_bounds__(256, 2)
void stageB(const float* __restrict__ z, const float* __restrict__ cb,
            const float* __restrict__ Bnp, const float* __restrict__ rowMin,
            const int* __restrict__ flagCnt, const int* __restrict__ flagList,
            int* __restrict__ candCnt, unsigned int* __restrict__ candList) {
    __shared__ float smem[2 * DK * LDSP];
    __shared__ int   frow[MT];
    __shared__ float rmin[MT];
    float (*zt)[LDSP] = (float (*)[LDSP])smem;
    float (*ct)[LDSP] = (float (*)[LDSP])(smem + DK * LDSP);

    const int nf = *flagCnt;
    const int R0 = blockIdx.x * MT;
    if (R0 >= nf) return;
    const int m = min(MT, nf - R0);

    const int tid = threadIdx.x;
    const int tx  = tid & 15;
    const int ty  = tid >> 4;

    if (tid < MT) {
        int fr = flagList[R0 + min(tid, m - 1)];   // pad with last real row (dups harmless)
        frow[tid] = fr;
        rmin[tid] = rowMin[fr];
    }
    __syncthreads();

    int   grr[8];
    float rm[8];
    #pragma unroll
    for (int i = 0; i < 8; ++i) { grr[i] = frow[ty * 8 + i]; rm[i] = rmin[ty * 8 + i]; }

    for (int kt = 0; kt < NE; kt += KT) {
        float acc[8][8];
        #pragma unroll
        for (int i = 0; i < 8; ++i)
            #pragma unroll
            for (int j = 0; j < 8; ++j) acc[i][j] = 0.f;

        for (int d0 = 0; d0 < D; d0 += DK) {
            __syncthreads();
            #pragma unroll
            for (int it = 0; it < 4; ++it) {
                int q  = tid + 256 * it;
                int r  = q >> 3;
                int dd = (q & 7) << 2;
                float4 zv = *(const float4*)(z  + (size_t)frow[r] * D + d0 + dd);
                float4 cv = *(const float4*)(cb + (size_t)(kt + r) * D + d0 + dd);
                zt[dd + 0][r] = zv.x; zt[dd + 1][r] = zv.y;
                zt[dd + 2][r] = zv.z; zt[dd + 3][r] = zv.w;
                ct[dd + 0][r] = cv.x; ct[dd + 1][r] = cv.y;
                ct[dd + 2][r] = cv.z; ct[dd + 3][r] = cv.w;
            }
            __syncthreads();
            #pragma unroll 4
            for (int dd = 0; dd < DK; ++dd) {
                float4 za = *(const float4*)&zt[dd][ty * 8];
                float4 zb = *(const float4*)&zt[dd][ty * 8 + 4];
                float4 ca = *(const float4*)&ct[dd][tx * 8];
                float4 cc = *(const float4*)&ct[dd][tx * 8 + 4];
                float zf[8] = {za.x, za.y, za.z, za.w, zb.x, zb.y, zb.z, zb.w};
                float cf[8] = {ca.x, ca.y, ca.z, ca.w, cc.x, cc.y, cc.z, cc.w};
                #pragma unroll
                for (int i = 0; i < 8; ++i)
                    #pragma unroll
                    for (int j = 0; j < 8; ++j)
                        acc[i][j] = fmaf(zf[i], cf[j], acc[i][j]);
            }
        }
        const int cbase = kt + tx * 8;
        float4 ea = *(const float4*)(Bnp + cbase);
        float4 eb = *(const float4*)(Bnp + cbase + 4);
        float e2v[8] = {ea.x, ea.y, ea.z, ea.w, eb.x, eb.y, eb.z, eb.w};
        #pragma unroll
        for (int i = 0; i < 8; ++i) {
            #pragma unroll
            for (int j = 0; j < 8; ++j) {
                float s = fmaf(-2.f, acc[i][j], e2v[j]);
                if (s <= rm[i] + DELTA) {
                    int p = atomicAdd(candCnt, 1);
                    if (p < CAND_CAP)
                        candList[p] = ((unsigned)grr[i] << 12) | (unsigned)(cbase + j);
                }
            }
        }
    }
}

// ---------------------------------------------------------------------------
// K5 (stage C): per candidate, bit-exact numpy score
//   s = fl( fl(Anp[r] + Bnp[k]) - 2*C_np(r,k) )
// folded into rowKey[r] via atomicMin on packed (fp32 bits << 32 | k):
// exactly np.argmin's min-value-then-lowest-index rule (s > 0 always).
__global__ void stageC(const float* __restrict__ z, const float* __restrict__ cb,
                       const float* __restrict__ Anp, const float* __restrict__ Bnp,
                       const int* __restrict__ candCnt,
                       const unsigned int* __restrict__ candList,
                       unsigned long long* __restrict__ rowKey) {
    int c = blockIdx.x * 256 + threadIdx.x;
    int n = min(*candCnt, CAND_CAP);
    if (c >= n) return;
    unsigned e = candList[c];
    int r = (int)(e >> 12);
    int k = (int)(e & 4095u);
    float C  = np_einsum_dot256(z + (size_t)r * D, cb + (size_t)k * D);
    float AB = __fadd_rn(Anp[r], Bnp[k]);
    float s  = __fsub_rn(AB, __fadd_rn(C, C));   // 2*C exact
    unsigned long long key = ((unsigned long long)__float_as_uint(s) << 32) | (unsigned)k;
    atomicMin(rowKey + r, key);
}

// ---------------------------------------------------------------------------
// K6: gather out[r] = cb[idx], idx from rowKey override (flagged) or idxArr.
__global__ void gather_kernel(const float* __restrict__ cb,
                              const int* __restrict__ idxArr,
                              const unsigned long long* __restrict__ rowKey,
                              float* __restrict__ out) {
    int r = blockIdx.x * 4 + (threadIdx.x >> 6);
    int l = threadIdx.x & 63;
    unsigned long long kv = rowKey[r];
    int ix = (kv != ~0ULL) ? (int)(kv & 0xFFFFFFFFull) : idxArr[r];
    *(float4*)(out + (size_t)r * D + l * 4) =
        *(const float4*)(cb + (size_t)ix * D + l * 4);
}

// ---------------------------------------------------------------------------
extern "C" void kernel_launch(void* const* d_in, const int* in_sizes, int n_in,
                              void* d_out, int out_size, void* d_ws, size_t ws_size,
                              hipStream_t stream) {
    const float* z  = (const float*)d_in[0];
    const float* cb = (const float*)d_in[1];
    float* out = (float*)d_out;
    const int nRows = in_sizes[0] / D;   // 65536

    char* w = (char*)d_ws;
    unsigned long long* rowKey = (unsigned long long*)w;              // 512 KB
    int*   idxArr   = (int*)  (w + 524288);                           // 256 KB
    float* rowMin   = (float*)(w + 786432);                           // 256 KB
    float* Anp      = (float*)(w + 1048576);                          // 256 KB
    int*   flagList = (int*)  (w + 1310720);                          // 256 KB
    float* Bnp      = (float*)(w + 1572864);                          // 16 KB
    unsigned int* candList = (unsigned int*)(w + 1589248);            // 512 KB
    int*   flagCnt  = (int*)  (w + 2113536);
    int*   candCnt  = flagCnt + 1;

    hipMemsetAsync(flagCnt, 0, 8, stream);
    bnp_kernel<<<NE / 256, 256, 0, stream>>>(cb, Bnp);
    anp_kernel<<<nRows / 256, 256, 0, stream>>>(z, Anp);
    stageA<<<nRows / MT, 256, 0, stream>>>(z, cb, Bnp, idxArr, rowMin, rowKey,
                                           flagCnt, flagList);
    stageB<<<nRows / MT, 256, 0, stream>>>(z, cb, Bnp, rowMin, flagCnt, flagList,
                                           candCnt, candList);
    stageC<<<CAND_CAP / 256, 256, 0, stream>>>(z, cb, Anp, Bnp, candCnt, candList, rowKey);
    gather_kernel<<<nRows / 4, 256, 0, stream>>>(cb, idxArr, rowKey, out);
}

// Round 3
// 968.810 us; speedup vs baseline: 3.3532x; 3.3532x over previous
//
#include <hip/hip_runtime.h>
#include <cfloat>
#include <climits>

// VectorQuantizer2: z [32,2048,256] fp32, codebook [4096,256] fp32.
#define D     256
#define NE    4096
#define MT    128      // rows per block tile
#define KT    128      // codes per k-tile (stageB)
#define DK    32       // d-chunk staged through LDS (stageB)
#define LDSP  132      // padded LDS leading dim (stageB)
#define NSPLIT 16      // stageB K-split factor
// DELTA must exceed np fp32 rounding envelope (2*half-ulp(~256)*2 = 6.13e-5)
// plus fast-path errors (split-bf16 MFMA ~2e-6, stageB fp32 ~2e-7).
#define DELTA     8e-5f
#define CAND_CAP  131072

typedef __attribute__((ext_vector_type(8))) short bf16x8;
typedef __attribute__((ext_vector_type(4))) float f32x4;

// ---------------------------------------------------------------------------
// bf16 helpers (RNE, bit-level; bf16 = top 16 bits of fp32)
__device__ __forceinline__ unsigned short f2bf(float x) {
    unsigned u = __float_as_uint(x);
    unsigned r = (u + 0x7FFFu + ((u >> 16) & 1u)) >> 16;
    return (unsigned short)r;
}
__device__ __forceinline__ float bf2f(unsigned short b) {
    return __uint_as_float(((unsigned)b) << 16);
}

// async global->LDS, 16B per lane; LDS dest = wave-uniform base + lane*16
__device__ __forceinline__ void stage16(const unsigned short* g, unsigned short* l) {
    __builtin_amdgcn_global_load_lds(
        (const __attribute__((address_space(1))) unsigned int*)g,
        (__attribute__((address_space(3))) unsigned int*)l, 16, 0, 0);
}

// ---------------------------------------------------------------------------
// numpy-bit-exact fp32 helpers. __fmul_rn/__fadd_rn are contraction barriers.
__device__ __forceinline__ float np_block128_sq(const float* __restrict__ p) {
    float r[8];
    #pragma unroll
    for (int j = 0; j < 8; ++j) r[j] = __fmul_rn(p[j], p[j]);
    #pragma unroll
    for (int i = 8; i < 128; i += 8)
        #pragma unroll
        for (int j = 0; j < 8; ++j) r[j] = __fadd_rn(r[j], __fmul_rn(p[i + j], p[i + j]));
    return __fadd_rn(__fadd_rn(__fadd_rn(r[0], r[1]), __fadd_rn(r[2], r[3])),
                     __fadd_rn(__fadd_rn(r[4], r[5]), __fadd_rn(r[6], r[7])));
}
__device__ __forceinline__ float np_sumsq256(const float* __restrict__ p) {
    return __fadd_rn(np_block128_sq(p), np_block128_sq(p + 128));
}
// np.einsum('nd,kd->nk', optimize=False) dot: SSE 4-lane, no FMA, 16/iter,
// chained muladd order p3,p2,p1,p0, SSE3 hadd (v0+v1)+(v2+v3).
__device__ __forceinline__ float np_einsum_dot256(const float* __restrict__ zr,
                                                  const float* __restrict__ er) {
    float v0 = 0.f, v1 = 0.f, v2 = 0.f, v3 = 0.f;
    for (int t = 0; t < 256; t += 16) {
        float4 a0 = *(const float4*)(zr + t);
        float4 a1 = *(const float4*)(zr + t + 4);
        float4 a2 = *(const float4*)(zr + t + 8);
        float4 a3 = *(const float4*)(zr + t + 12);
        float4 b0 = *(const float4*)(er + t);
        float4 b1 = *(const float4*)(er + t + 4);
        float4 b2 = *(const float4*)(er + t + 8);
        float4 b3 = *(const float4*)(er + t + 12);
        v0 = __fadd_rn(v0, __fmul_rn(a3.x, b3.x));
        v1 = __fadd_rn(v1, __fmul_rn(a3.y, b3.y));
        v2 = __fadd_rn(v2, __fmul_rn(a3.z, b3.z));
        v3 = __fadd_rn(v3, __fmul_rn(a3.w, b3.w));
        v0 = __fadd_rn(v0, __fmul_rn(a2.x, b2.x));
        v1 = __fadd_rn(v1, __fmul_rn(a2.y, b2.y));
        v2 = __fadd_rn(v2, __fmul_rn(a2.z, b2.z));
        v3 = __fadd_rn(v3, __fmul_rn(a2.w, b2.w));
        v0 = __fadd_rn(v0, __fmul_rn(a1.x, b1.x));
        v1 = __fadd_rn(v1, __fmul_rn(a1.y, b1.y));
        v2 = __fadd_rn(v2, __fmul_rn(a1.z, b1.z));
        v3 = __fadd_rn(v3, __fmul_rn(a1.w, b1.w));
        v0 = __fadd_rn(v0, __fmul_rn(a0.x, b0.x));
        v1 = __fadd_rn(v1, __fmul_rn(a0.y, b0.y));
        v2 = __fadd_rn(v2, __fmul_rn(a0.z, b0.z));
        v3 = __fadd_rn(v3, __fmul_rn(a0.w, b0.w));
    }
    return __fadd_rn(__fadd_rn(v0, v1), __fadd_rn(v2, v3));
}

// ---------------------------------------------------------------------------
// K1: Bnp[k] = np-exact sum(cb[k]**2);  K2: Anp[r] = np-exact sum(z[r]**2)
__global__ void bnp_kernel(const float* __restrict__ cb, float* __restrict__ Bnp) {
    int k = blockIdx.x * 256 + threadIdx.x;
    if (k < NE) Bnp[k] = np_sumsq256(cb + (size_t)k * D);
}
__global__ void anp_kernel(const float* __restrict__ z, float* __restrict__ Anp) {
    int r = blockIdx.x * 256 + threadIdx.x;
    Anp[r] = np_sumsq256(z + (size_t)r * D);
}

// ---------------------------------------------------------------------------
// K3: split fp32 -> [hi(256) | lo(256)] bf16 per row. hi=bf16(x), lo=bf16(x-hi).
__global__ void split_kernel(const float* __restrict__ x,
                             unsigned short* __restrict__ y, int nRows) {
    int t = blockIdx.x * 256 + threadIdx.x;
    if (t >= nRows * 64) return;
    int row = t >> 6, c4 = (t & 63) << 2;
    float4 v = *(const float4*)(x + (size_t)row * D + c4);
    ushort4 h, l;
    h.x = f2bf(v.x); h.y = f2bf(v.y); h.z = f2bf(v.z); h.w = f2bf(v.w);
    l.x = f2bf(v.x - bf2f(h.x)); l.y = f2bf(v.y - bf2f(h.y));
    l.z = f2bf(v.z - bf2f(h.z)); l.w = f2bf(v.w - bf2f(h.w));
    *(ushort4*)(y + (size_t)row * 512 + c4) = h;
    *(ushort4*)(y + (size_t)row * 512 + 256 + c4) = l;
}

// ---------------------------------------------------------------------------
// K4 (stage A): split-bf16 3-pass MFMA score GEMM + per-row top-2.
// dot = Ah·Bh + Ah·Bl + Al·Bh;  s = Bnp[k] - 2*dot.
// Block: 256 thr = 4 waves (2x2), tile 128 rows x 128 codes, wave 64x64,
// 16x16x32 bf16 MFMA, BK=32, global_load_lds(16B) staging (m97 pattern).
__global__ __launch_bounds__(256, 2)
void stageA_mfma(const unsigned short* __restrict__ z2,
                 const unsigned short* __restrict__ cb2,
                 const float* __restrict__ Bnp, int* __restrict__ idxArr,
                 float* __restrict__ rowMin, unsigned long long* __restrict__ rowKey,
                 int* __restrict__ flagCnt, int* __restrict__ flagList) {
    __shared__ unsigned short lds[4 * 4096];   // Ah|Al|Bh|Bl, 128x32 bf16 each (32 KB)
    unsigned short* Ah = lds;
    unsigned short* Al = lds + 4096;
    unsigned short* Bh = lds + 8192;
    unsigned short* Bl = lds + 12288;

    const int tid  = threadIdx.x;
    const int wid  = tid >> 6;
    const int lane = tid & 63;
    const int ln   = lane & 15;      // C col / A,B m-n index
    const int qd   = lane >> 4;      // quad
    const int wm   = wid & 1;        // wave row
    const int wn   = wid >> 1;       // wave col
    const int R0   = blockIdx.x * MT;

    float best1[16], best2[16];
    int   bidx[16];
    #pragma unroll
    for (int i = 0; i < 16; ++i) { best1[i] = FLT_MAX; best2[i] = FLT_MAX; bidx[i] = 0; }

    for (int ct = 0; ct < NE / 128; ++ct) {
        const int C0 = ct * 128;
        f32x4 acc[4][4];
        #pragma unroll
        for (int i = 0; i < 4; ++i)
            #pragma unroll
            for (int j = 0; j < 4; ++j) acc[i][j] = (f32x4){0.f, 0.f, 0.f, 0.f};

        for (int kc = 0; kc < 8; ++kc) {
            __syncthreads();   // previous iteration's LDS reads done
            #pragma unroll
            for (int i = 0; i < 2; ++i) {
                int q = i * 256 + tid;           // 0..511
                int row = q >> 2, seg = q & 3;   // row 0..127, 16B-seg 0..3
                size_t eo = (size_t)(kc * 32 + seg * 8);
                const unsigned short* gah = z2  + (size_t)(R0 + row) * 512 + eo;
                const unsigned short* gbh = cb2 + (size_t)(C0 + row) * 512 + eo;
                unsigned short* ldst = (unsigned short*)0 + i * 2048 + wid * 512;
                stage16(gah,       Ah + i * 2048 + wid * 512);
                stage16(gah + 256, Al + i * 2048 + wid * 512);
                stage16(gbh,       Bh + i * 2048 + wid * 512);
                stage16(gbh + 256, Bl + i * 2048 + wid * 512);
                (void)ldst;
            }
            __syncthreads();   // drains vmcnt (global_load_lds complete)

            bf16x8 fah[4], fal[4], fbh[4], fbl[4];
            const int ao = (wm * 64 + ln) * 32 + qd * 8;
            const int bo = (wn * 64 + ln) * 32 + qd * 8;
            #pragma unroll
            for (int t = 0; t < 4; ++t) {
                fah[t] = *(const bf16x8*)(Ah + ao + t * 512);
                fal[t] = *(const bf16x8*)(Al + ao + t * 512);
                fbh[t] = *(const bf16x8*)(Bh + bo + t * 512);
                fbl[t] = *(const bf16x8*)(Bl + bo + t * 512);
            }
            #pragma unroll
            for (int i = 0; i < 4; ++i)
                #pragma unroll
                for (int j = 0; j < 4; ++j) {
                    acc[i][j] = __builtin_amdgcn_mfma_f32_16x16x32_bf16(fah[i], fbh[j], acc[i][j], 0, 0, 0);
                    acc[i][j] = __builtin_amdgcn_mfma_f32_16x16x32_bf16(fah[i], fbl[j], acc[i][j], 0, 0, 0);
                    acc[i][j] = __builtin_amdgcn_mfma_f32_16x16x32_bf16(fal[i], fbh[j], acc[i][j], 0, 0, 0);
                }
        }

        // epilogue: fold 64 scores into per-lane top-2 (cols ascend => '<' keeps lowest idx)
        #pragma unroll
        for (int tn = 0; tn < 4; ++tn) {
            int col = C0 + wn * 64 + tn * 16 + ln;
            float bn = Bnp[col];
            #pragma unroll
            for (int tm = 0; tm < 4; ++tm) {
                f32x4 a = acc[tm][tn];
                #pragma unroll
                for (int r = 0; r < 4; ++r) {
                    float s = fmaf(-2.f, a[r], bn);
                    int ii = tm * 4 + r;
                    if (s < best1[ii]) { best2[ii] = best1[ii]; best1[ii] = s; bidx[ii] = col; }
                    else if (s < best2[ii]) best2[ii] = s;
                }
            }
        }
    }

    // in-wave merge across the 16 lanes of each quad (same rows, different cols)
    #pragma unroll
    for (int mask = 1; mask < 16; mask <<= 1) {
        #pragma unroll
        for (int ii = 0; ii < 16; ++ii) {
            float c1 = __shfl_xor(best1[ii], mask);
            float c2 = __shfl_xor(best2[ii], mask);
            int   ci = __shfl_xor(bidx[ii], mask);
            if (c1 < best1[ii] || (c1 == best1[ii] && ci < bidx[ii])) {
                best2[ii] = fminf(best1[ii], c2);
                best1[ii] = c1; bidx[ii] = ci;
            } else {
                best2[ii] = fminf(best2[ii], c1);
            }
        }
    }
    __syncthreads();   // LDS reuse for cross-wave merge
    float* mb1 = (float*)lds;                 // [128][2]
    float* mb2 = mb1 + 256;
    int*   mix = (int*)(mb2 + 256);
    if (ln == 0) {
        #pragma unroll
        for (int tm = 0; tm < 4; ++tm)
            #pragma unroll
            for (int r = 0; r < 4; ++r) {
                int row = wm * 64 + tm * 16 + qd * 4 + r;
                mb1[row * 2 + wn] = best1[tm * 4 + r];
                mb2[row * 2 + wn] = best2[tm * 4 + r];
                mix[row * 2 + wn] = bidx[tm * 4 + r];
            }
    }
    __syncthreads();
    if (tid < MT) {
        int r = tid;
        float b1 = mb1[r * 2], b2v = mb2[r * 2]; int ix = mix[r * 2];
        float c1 = mb1[r * 2 + 1], c2 = mb2[r * 2 + 1]; int ci = mix[r * 2 + 1];
        if (c1 < b1 || (c1 == b1 && ci < ix)) { b2v = fminf(b1, c2); b1 = c1; ix = ci; }
        else b2v = fminf(b2v, c1);
        idxArr[R0 + r] = ix;
        rowMin[R0 + r] = b1;
        rowKey[R0 + r] = ~0ULL;
        if (b2v - b1 <= DELTA) {
            int p = atomicAdd(flagCnt, 1);
            flagList[p] = R0 + r;
        }
    }
}

// ---------------------------------------------------------------------------
// K5 (stage B): flagged-row rescan, fp32, K-split by blockIdx.y (NSPLIT ranges).
// Appends every code with s~ <= rowMin + DELTA as a candidate.
__global__ __launch_bounds__(256, 2)
void stageB(const float* __restrict__ z, const float* __restrict__ cb,
            const float* __restrict__ Bnp, const float* __restrict__ rowMin,
            const int* __restrict__ flagCnt, const int* __restrict__ flagList,
            int* __restrict__ candCnt, unsigned int* __restrict__ candList) {
    __shared__ float smem[2 * DK * LDSP];
    __shared__ int   frow[MT];
    __shared__ float rmin[MT];
    float (*zt)[LDSP] = (float (*)[LDSP])smem;
    float (*ct)[LDSP] = (float (*)[LDSP])(smem + DK * LDSP);

    const int nf = *flagCnt;
    const int R0 = blockIdx.x * MT;
    if (R0 >= nf) return;
    const int m = min(MT, nf - R0);

    const int tid = threadIdx.x;
    const int tx  = tid & 15;
    const int ty  = tid >> 4;

    if (tid < MT) {
        int fr = flagList[R0 + min(tid, m - 1)];   // pad w/ last real row (dups harmless)
        frow[tid] = fr;
        rmin[tid] = rowMin[fr];
    }
    __syncthreads();

    int   grr[8];
    float rm[8];
    #pragma unroll
    for (int i = 0; i < 8; ++i) { grr[i] = frow[ty * 8 + i]; rm[i] = rmin[ty * 8 + i]; }

    const int ktBeg = blockIdx.y * (NE / NSPLIT);
    const int ktEnd = ktBeg + NE / NSPLIT;
    for (int kt = ktBeg; kt < ktEnd; kt += KT) {
        float acc[8][8];
        #pragma unroll
        for (int i = 0; i < 8; ++i)
            #pragma unroll
            for (int j = 0; j < 8; ++j) acc[i][j] = 0.f;

        for (int d0 = 0; d0 < D; d0 += DK) {
            __syncthreads();
            #pragma unroll
            for (int it = 0; it < 4; ++it) {
                int q  = tid + 256 * it;
                int r  = q >> 3;
                int dd = (q & 7) << 2;
                float4 zv = *(const float4*)(z  + (size_t)frow[r] * D + d0 + dd);
                float4 cv = *(const float4*)(cb + (size_t)(kt + r) * D + d0 + dd);
                zt[dd + 0][r] = zv.x; zt[dd + 1][r] = zv.y;
                zt[dd + 2][r] = zv.z; zt[dd + 3][r] = zv.w;
                ct[dd + 0][r] = cv.x; ct[dd + 1][r] = cv.y;
                ct[dd + 2][r] = cv.z; ct[dd + 3][r] = cv.w;
            }
            __syncthreads();
            #pragma unroll 4
            for (int dd = 0; dd < DK; ++dd) {
                float4 za = *(const float4*)&zt[dd][ty * 8];
                float4 zb = *(const float4*)&zt[dd][ty * 8 + 4];
                float4 ca = *(const float4*)&ct[dd][tx * 8];
                float4 cc = *(const float4*)&ct[dd][tx * 8 + 4];
                float zf[8] = {za.x, za.y, za.z, za.w, zb.x, zb.y, zb.z, zb.w};
                float cf[8] = {ca.x, ca.y, ca.z, ca.w, cc.x, cc.y, cc.z, cc.w};
                #pragma unroll
                for (int i = 0; i < 8; ++i)
                    #pragma unroll
                    for (int j = 0; j < 8; ++j)
                        acc[i][j] = fmaf(zf[i], cf[j], acc[i][j]);
            }
        }
        const int cbase = kt + tx * 8;
        float4 ea = *(const float4*)(Bnp + cbase);
        float4 eb = *(const float4*)(Bnp + cbase + 4);
        float e2v[8] = {ea.x, ea.y, ea.z, ea.w, eb.x, eb.y, eb.z, eb.w};
        #pragma unroll
        for (int i = 0; i < 8; ++i) {
            #pragma unroll
            for (int j = 0; j < 8; ++j) {
                float s = fmaf(-2.f, acc[i][j], e2v[j]);
                if (s <= rm[i] + DELTA) {
                    int p = atomicAdd(candCnt, 1);
                    if (p < CAND_CAP)
                        candList[p] = ((unsigned)grr[i] << 12) | (unsigned)(cbase + j);
                }
            }
        }
    }
}

// ---------------------------------------------------------------------------
// K6 (stage C): bit-exact numpy score per candidate, atomicMin((bits<<32)|k).
__global__ void stageC(const float* __restrict__ z, const float* __restrict__ cb,
                       const float* __restrict__ Anp, const float* __restrict__ Bnp,
                       const int* __restrict__ candCnt,
                       const unsigned int* __restrict__ candList,
                       unsigned long long* __restrict__ rowKey) {
    int c = blockIdx.x * 256 + threadIdx.x;
    int n = min(*candCnt, CAND_CAP);
    if (c >= n) return;
    unsigned e = candList[c];
    int r = (int)(e >> 12);
    int k = (int)(e & 4095u);
    float C  = np_einsum_dot256(z + (size_t)r * D, cb + (size_t)k * D);
    float AB = __fadd_rn(Anp[r], Bnp[k]);
    float s  = __fsub_rn(AB, __fadd_rn(C, C));
    unsigned long long key = ((unsigned long long)__float_as_uint(s) << 32) | (unsigned)k;
    atomicMin(rowKey + r, key);
}

// ---------------------------------------------------------------------------
// K7: gather out[r] = cb[idx]; idx from rowKey override (flagged) or idxArr.
__global__ void gather_kernel(const float* __restrict__ cb,
                              const int* __restrict__ idxArr,
                              const unsigned long long* __restrict__ rowKey,
                              float* __restrict__ out) {
    int r = blockIdx.x * 4 + (threadIdx.x >> 6);
    int l = threadIdx.x & 63;
    unsigned long long kv = rowKey[r];
    int ix = (kv != ~0ULL) ? (int)(kv & 0xFFFFFFFFull) : idxArr[r];
    *(float4*)(out + (size_t)r * D + l * 4) =
        *(const float4*)(cb + (size_t)ix * D + l * 4);
}

// ---------------------------------------------------------------------------
extern "C" void kernel_launch(void* const* d_in, const int* in_sizes, int n_in,
                              void* d_out, int out_size, void* d_ws, size_t ws_size,
                              hipStream_t stream) {
    const float* z  = (const float*)d_in[0];
    const float* cb = (const float*)d_in[1];
    float* out = (float*)d_out;
    const int nRows = in_sizes[0] / D;   // 65536

    char* w = (char*)d_ws;
    unsigned short* z2  = (unsigned short*)w;                         // 64 MB
    unsigned short* cb2 = (unsigned short*)(w + 67108864);            // 4 MB
    unsigned long long* rowKey = (unsigned long long*)(w + 71303168); // 512 KB
    int*   idxArr   = (int*)  (w + 71827456);                         // 256 KB
    float* rowMin   = (float*)(w + 72089600);                         // 256 KB
    float* Anp      = (float*)(w + 72351744);                         // 256 KB
    int*   flagList = (int*)  (w + 72613888);                         // 256 KB
    float* Bnp      = (float*)(w + 72876032);                         // 16 KB
    unsigned int* candList = (unsigned int*)(w + 72892416);           // 512 KB
    int*   flagCnt  = (int*)  (w + 73416704);
    int*   candCnt  = flagCnt + 1;

    hipMemsetAsync(flagCnt, 0, 8, stream);
    bnp_kernel<<<NE / 256, 256, 0, stream>>>(cb, Bnp);
    anp_kernel<<<nRows / 256, 256, 0, stream>>>(z, Anp);
    split_kernel<<<nRows * 64 / 256, 256, 0, stream>>>(z, z2, nRows);
    split_kernel<<<NE * 64 / 256, 256, 0, stream>>>(cb, cb2, NE);
    stageA_mfma<<<nRows / MT, 256, 0, stream>>>(z2, cb2, Bnp, idxArr, rowMin,
                                                rowKey, flagCnt, flagList);
    stageB<<<dim3(nRows / MT, NSPLIT), 256, 0, stream>>>(z, cb, Bnp, rowMin,
                                                         flagCnt, flagList,
                                                         candCnt, candList);
    stageC<<<CAND_CAP / 256, 256, 0, stream>>>(z, cb, Anp, Bnp, candCnt, candList, rowKey);
    gather_kernel<<<nRows / 4, 256, 0, stream>>>(cb, idxArr, rowKey, out);
}

// Round 5
// 783.347 us; speedup vs baseline: 4.1471x; 1.2368x over previous
//
#include <hip/hip_runtime.h>
#include <hip/hip_fp16.h>
#include <cfloat>
#include <climits>

// VectorQuantizer2: z [32,2048,256] fp32, codebook [4096,256] fp32.
#define D     256
#define NE    4096
#define MT    64       // rows per block (stageA); A panel LDS-resident
#define AS    264      // A panel LDS row stride in halves (528 B: 16B-aligned, 2-way free)
#define BS    40       // B tile  LDS row stride in halves  (80 B: 16B-aligned, 2-way free)
#define BMT   128      // rows per block tile (stageB)
#define KT    128      // codes per k-tile (stageB)
#define DK    32       // d-chunk (stageB)
#define LDSP  132      // padded LDS leading dim (stageB)
#define NSPLIT 16      // stageB K-split factor
// DELTA covers worst-case np fp32 envelope (2*4.6e-5) + fp16 single-pass dot
// worst bound (~5e-5 score) + fp32 stageB error.
#define DELTA     1.5e-4f
#define CAND_CAP  131072

typedef _Float16 f16x8 __attribute__((ext_vector_type(8)));
typedef __attribute__((ext_vector_type(4))) float f32x4;

// ---------------------------------------------------------------------------
// numpy-bit-exact fp32 helpers. __fmul_rn/__fadd_rn are contraction barriers.
__device__ __forceinline__ float np_block128_sq(const float* __restrict__ p) {
    float r[8];
    #pragma unroll
    for (int j = 0; j < 8; ++j) r[j] = __fmul_rn(p[j], p[j]);
    #pragma unroll
    for (int i = 8; i < 128; i += 8)
        #pragma unroll
        for (int j = 0; j < 8; ++j) r[j] = __fadd_rn(r[j], __fmul_rn(p[i + j], p[i + j]));
    return __fadd_rn(__fadd_rn(__fadd_rn(r[0], r[1]), __fadd_rn(r[2], r[3])),
                     __fadd_rn(__fadd_rn(r[4], r[5]), __fadd_rn(r[6], r[7])));
}
__device__ __forceinline__ float np_sumsq256(const float* __restrict__ p) {
    return __fadd_rn(np_block128_sq(p), np_block128_sq(p + 128));
}
// np.einsum('nd,kd->nk', optimize=False) dot: SSE 4-lane, no FMA, 16/iter,
// chained muladd order p3,p2,p1,p0, SSE3 hadd (v0+v1)+(v2+v3).
__device__ __forceinline__ float np_einsum_dot256(const float* __restrict__ zr,
                                                  const float* __restrict__ er) {
    float v0 = 0.f, v1 = 0.f, v2 = 0.f, v3 = 0.f;
    for (int t = 0; t < 256; t += 16) {
        float4 a0 = *(const float4*)(zr + t);
        float4 a1 = *(const float4*)(zr + t + 4);
        float4 a2 = *(const float4*)(zr + t + 8);
        float4 a3 = *(const float4*)(zr + t + 12);
        float4 b0 = *(const float4*)(er + t);
        float4 b1 = *(const float4*)(er + t + 4);
        float4 b2 = *(const float4*)(er + t + 8);
        float4 b3 = *(const float4*)(er + t + 12);
        v0 = __fadd_rn(v0, __fmul_rn(a3.x, b3.x));
        v1 = __fadd_rn(v1, __fmul_rn(a3.y, b3.y));
        v2 = __fadd_rn(v2, __fmul_rn(a3.z, b3.z));
        v3 = __fadd_rn(v3, __fmul_rn(a3.w, b3.w));
        v0 = __fadd_rn(v0, __fmul_rn(a2.x, b2.x));
        v1 = __fadd_rn(v1, __fmul_rn(a2.y, b2.y));
        v2 = __fadd_rn(v2, __fmul_rn(a2.z, b2.z));
        v3 = __fadd_rn(v3, __fmul_rn(a2.w, b2.w));
        v0 = __fadd_rn(v0, __fmul_rn(a1.x, b1.x));
        v1 = __fadd_rn(v1, __fmul_rn(a1.y, b1.y));
        v2 = __fadd_rn(v2, __fmul_rn(a1.z, b1.z));
        v3 = __fadd_rn(v3, __fmul_rn(a1.w, b1.w));
        v0 = __fadd_rn(v0, __fmul_rn(a0.x, b0.x));
        v1 = __fadd_rn(v1, __fmul_rn(a0.y, b0.y));
        v2 = __fadd_rn(v2, __fmul_rn(a0.z, b0.z));
        v3 = __fadd_rn(v3, __fmul_rn(a0.w, b0.w));
    }
    return __fadd_rn(__fadd_rn(v0, v1), __fadd_rn(v2, v3));
}

// ---------------------------------------------------------------------------
// K1: Bnp[k] = np-exact sum(cb[k]**2)
__global__ void bnp_kernel(const float* __restrict__ cb, float* __restrict__ Bnp) {
    int k = blockIdx.x * 256 + threadIdx.x;
    if (k < NE) Bnp[k] = np_sumsq256(cb + (size_t)k * D);
}

// K2: fp32 -> fp16 (RNE), optional exact pow2 scale.
__global__ void tof16_kernel(const float* __restrict__ x,
                             unsigned short* __restrict__ y, float scale, int n4) {
    int t = blockIdx.x * 256 + threadIdx.x;
    if (t >= n4) return;
    float4 v = *(const float4*)(x + (size_t)t * 4);
    ushort4 o;
    o.x = __half_as_ushort(__float2half_rn(v.x * scale));
    o.y = __half_as_ushort(__float2half_rn(v.y * scale));
    o.z = __half_as_ushort(__float2half_rn(v.z * scale));
    o.w = __half_as_ushort(__float2half_rn(v.w * scale));
    *(ushort4*)(y + (size_t)t * 4) = o;
}

// ---------------------------------------------------------------------------
// K3 (stage A): single-pass fp16 MFMA score GEMM + per-row top-2.
// acc = z_f16 · (4096*cb)_f16 ;  s = Bnp[k] - 2^-11 * acc.
// Block: 256 thr = 4 waves (2x2), tile 64 rows x 128 codes, wave 32x64.
// A panel (64x256 f16, padded stride 264) LDS-resident, staged once.
// B tiles (128x32 f16, padded stride 40) staged per kc via VGPR+ds_write.
__global__ __launch_bounds__(256, 3)
void stageA_f16(const unsigned short* __restrict__ z2,
                const unsigned short* __restrict__ cb2,
                const float* __restrict__ Bnp, int* __restrict__ idxArr,
                float* __restrict__ rowMin, unsigned long long* __restrict__ rowKey,
                int* __restrict__ flagCnt, int* __restrict__ flagList) {
    __shared__ unsigned short lds[MT * AS + 128 * BS];   // 33792 + 10240 = 44032 B
    unsigned short* Ap = lds;            // A panel [64][264]
    unsigned short* Bt = lds + MT * AS;  // B tile  [128][40]

    const int tid  = threadIdx.x;
    const int wid  = tid >> 6;
    const int lane = tid & 63;
    const int ln   = lane & 15;      // col within 16x16 tile
    const int qd   = lane >> 4;      // quad
    const int wm   = wid & 1;        // wave row (32 rows each)
    const int wn   = wid >> 1;       // wave col (64 codes each)
    const int R0   = blockIdx.x * MT;

    // ---- stage A panel once: 64 rows x 32 segs(16B) = 2048 segs / 256 thr
    #pragma unroll
    for (int i = 0; i < 8; ++i) {
        int q = tid + 256 * i;
        int row = q >> 5, seg = q & 31;
        uint4 v = *(const uint4*)(z2 + (size_t)(R0 + row) * 256 + seg * 8);
        *(uint4*)(Ap + row * AS + seg * 8) = v;
    }
    // per-thread B staging map: 128 codes x 4 segs = 512 / 256 thr = 2 each
    const int bc0 = tid >> 2, bs0 = tid & 3;          // i=0
    const int bc1 = (tid + 256) >> 2, bs1 = tid & 3;  // i=1

    float best1[8], best2[8];
    int   bidx[8];
    #pragma unroll
    for (int i = 0; i < 8; ++i) { best1[i] = FLT_MAX; best2[i] = FLT_MAX; bidx[i] = 0; }

    const int aoff = (wm * 32 + ln) * AS + qd * 8;           // + mt*16*AS + kc*32
    const int boff = MT * AS + (wn * 64 + ln) * BS + qd * 8; // + nt*16*BS

    for (int ct = 0; ct < NE / 128; ++ct) {
        const int C0 = ct * 128;
        const unsigned short* pB = cb2 + (size_t)C0 * 256;
        f32x4 acc[2][4];
        #pragma unroll
        for (int i = 0; i < 2; ++i)
            #pragma unroll
            for (int j = 0; j < 4; ++j) acc[i][j] = (f32x4){0.f, 0.f, 0.f, 0.f};

        #pragma unroll
        for (int kc = 0; kc < 8; ++kc) {
            uint4 v0 = *(const uint4*)(pB + (size_t)bc0 * 256 + kc * 32 + bs0 * 8);
            uint4 v1 = *(const uint4*)(pB + (size_t)bc1 * 256 + kc * 32 + bs1 * 8);
            __syncthreads();   // prior kc's B reads complete
            *(uint4*)(Bt + bc0 * BS + bs0 * 8) = v0;
            *(uint4*)(Bt + bc1 * BS + bs1 * 8) = v1;
            __syncthreads();   // B tile visible

            f16x8 fa[2], fb[4];
            #pragma unroll
            for (int mt = 0; mt < 2; ++mt)
                fa[mt] = *(const f16x8*)(Ap + aoff + mt * 16 * AS + kc * 32);
            #pragma unroll
            for (int nt = 0; nt < 4; ++nt)
                fb[nt] = *(const f16x8*)(lds + boff + nt * 16 * BS);
            #pragma unroll
            for (int mt = 0; mt < 2; ++mt)
                #pragma unroll
                for (int nt = 0; nt < 4; ++nt)
                    acc[mt][nt] = __builtin_amdgcn_mfma_f32_16x16x32_f16(
                        fa[mt], fb[nt], acc[mt][nt], 0, 0, 0);
        }

        // epilogue: s = Bnp - 2^-11 * acc; fold into per-lane top-2
        #pragma unroll
        for (int nt = 0; nt < 4; ++nt) {
            int col = C0 + wn * 64 + nt * 16 + ln;
            float bn = Bnp[col];
            #pragma unroll
            for (int mt = 0; mt < 2; ++mt) {
                f32x4 a = acc[mt][nt];
                #pragma unroll
                for (int r = 0; r < 4; ++r) {
                    float s = fmaf(-4.8828125e-4f, a[r], bn);   // -2^-11 exact
                    int ii = mt * 4 + r;
                    if (s < best1[ii]) { best2[ii] = best1[ii]; best1[ii] = s; bidx[ii] = col; }
                    else if (s < best2[ii]) best2[ii] = s;
                }
            }
        }
    }

    // merge across the 16 ln-lanes (same rows, different cols); '<'+idx keeps np rule
    #pragma unroll
    for (int mask = 1; mask < 16; mask <<= 1) {
        #pragma unroll
        for (int ii = 0; ii < 8; ++ii) {
            float c1 = __shfl_xor(best1[ii], mask);
            float c2 = __shfl_xor(best2[ii], mask);
            int   ci = __shfl_xor(bidx[ii], mask);
            if (c1 < best1[ii] || (c1 == best1[ii] && ci < bidx[ii])) {
                best2[ii] = fminf(best1[ii], c2);
                best1[ii] = c1; bidx[ii] = ci;
            } else {
                best2[ii] = fminf(best2[ii], c1);
            }
        }
    }
    __syncthreads();   // reuse LDS for cross-wave merge
    float* mb1 = (float*)lds;          // [64][2]
    float* mb2 = mb1 + 128;
    int*   mix = (int*)(mb2 + 128);
    if (ln == 0) {
        #pragma unroll
        for (int mt = 0; mt < 2; ++mt)
            #pragma unroll
            for (int r = 0; r < 4; ++r) {
                int row = wm * 32 + mt * 16 + qd * 4 + r;
                mb1[row * 2 + wn] = best1[mt * 4 + r];
                mb2[row * 2 + wn] = best2[mt * 4 + r];
                mix[row * 2 + wn] = bidx[mt * 4 + r];
            }
    }
    __syncthreads();
    if (tid < MT) {
        int r = tid;
        float b1 = mb1[r * 2], b2v = mb2[r * 2]; int ix = mix[r * 2];
        float c1 = mb1[r * 2 + 1], c2 = mb2[r * 2 + 1]; int ci = mix[r * 2 + 1];
        if (c1 < b1 || (c1 == b1 && ci < ix)) { b2v = fminf(b1, c2); b1 = c1; ix = ci; }
        else b2v = fminf(b2v, c1);
        idxArr[R0 + r] = ix;
        rowMin[R0 + r] = b1;
        rowKey[R0 + r] = ~0ULL;
        if (b2v - b1 <= DELTA) {
            int p = atomicAdd(flagCnt, 1);
            flagList[p] = R0 + r;
        }
    }
}

// ---------------------------------------------------------------------------
// K4 (stage B): flagged-row rescan, fp32, K-split by blockIdx.y.
// Appends every code with s~ <= rowMin + DELTA as a candidate.
__global__ __launch_bounds__(256, 2)
void stageB(const float* __restrict__ z, const float* __restrict__ cb,
            const float* __restrict__ Bnp, const float* __restrict__ rowMin,
            const int* __restrict__ flagCnt, const int* __restrict__ flagList,
            int* __restrict__ candCnt, unsigned int* __restrict__ candList) {
    __shared__ float smem[2 * DK * LDSP];
    __shared__ int   frow[BMT];
    __shared__ float rmin[BMT];
    float (*zt)[LDSP] = (float (*)[LDSP])smem;
    float (*ct)[LDSP] = (float (*)[LDSP])(smem + DK * LDSP);

    const int nf = *flagCnt;
    const int R0 = blockIdx.x * BMT;
    if (R0 >= nf) return;
    const int m = min(BMT, nf - R0);

    const int tid = threadIdx.x;
    const int tx  = tid & 15;
    const int ty  = tid >> 4;

    if (tid < BMT) {
        int fr = flagList[R0 + min(tid, m - 1)];   // pad w/ last real row (dups harmless)
        frow[tid] = fr;
        rmin[tid] = rowMin[fr];
    }
    __syncthreads();

    int   grr[8];
    float rm[8];
    #pragma unroll
    for (int i = 0; i < 8; ++i) { grr[i] = frow[ty * 8 + i]; rm[i] = rmin[ty * 8 + i]; }

    const int ktBeg = blockIdx.y * (NE / NSPLIT);
    const int ktEnd = ktBeg + NE / NSPLIT;
    for (int kt = ktBeg; kt < ktEnd; kt += KT) {
        float acc[8][8];
        #pragma unroll
        for (int i = 0; i < 8; ++i)
            #pragma unroll
            for (int j = 0; j < 8; ++j) acc[i][j] = 0.f;

        for (int d0 = 0; d0 < D; d0 += DK) {
            __syncthreads();
            #pragma unroll
            for (int it = 0; it < 4; ++it) {
                int q  = tid + 256 * it;
                int r  = q >> 3;
                int dd = (q & 7) << 2;
                float4 zv = *(const float4*)(z  + (size_t)frow[r] * D + d0 + dd);
                float4 cv = *(const float4*)(cb + (size_t)(kt + r) * D + d0 + dd);
                zt[dd + 0][r] = zv.x; zt[dd + 1][r] = zv.y;
                zt[dd + 2][r] = zv.z; zt[dd + 3][r] = zv.w;
                ct[dd + 0][r] = cv.x; ct[dd + 1][r] = cv.y;
                ct[dd + 2][r] = cv.z; ct[dd + 3][r] = cv.w;
            }
            __syncthreads();
            #pragma unroll 4
            for (int dd = 0; dd < DK; ++dd) {
                float4 za = *(const float4*)&zt[dd][ty * 8];
                float4 zb = *(const float4*)&zt[dd][ty * 8 + 4];
                float4 ca = *(const float4*)&ct[dd][tx * 8];
                float4 cc = *(const float4*)&ct[dd][tx * 8 + 4];
                float zf[8] = {za.x, za.y, za.z, za.w, zb.x, zb.y, zb.z, zb.w};
                float cf[8] = {ca.x, ca.y, ca.z, ca.w, cc.x, cc.y, cc.z, cc.w};
                #pragma unroll
                for (int i = 0; i < 8; ++i)
                    #pragma unroll
                    for (int j = 0; j < 8; ++j)
                        acc[i][j] = fmaf(zf[i], cf[j], acc[i][j]);
            }
        }
        const int cbase = kt + tx * 8;
        float4 ea = *(const float4*)(Bnp + cbase);
        float4 eb = *(const float4*)(Bnp + cbase + 4);
        float e2v[8] = {ea.x, ea.y, ea.z, ea.w, eb.x, eb.y, eb.z, eb.w};
        #pragma unroll
        for (int i = 0; i < 8; ++i) {
            #pragma unroll
            for (int j = 0; j < 8; ++j) {
                float s = fmaf(-2.f, acc[i][j], e2v[j]);
                if (s <= rm[i] + DELTA) {
                    int p = atomicAdd(candCnt, 1);
                    if (p < CAND_CAP)
                        candList[p] = ((unsigned)grr[i] << 12) | (unsigned)(cbase + j);
                }
            }
        }
    }
}

// ---------------------------------------------------------------------------
// K5 (stage C): bit-exact numpy score per candidate (||z||^2 computed inline),
// folded via atomicMin((fp32 bits << 32) | k) = np's min-then-lowest-idx rule.
__global__ void stageC(const float* __restrict__ z, const float* __restrict__ cb,
                       const float* __restrict__ Bnp,
                       const int* __restrict__ candCnt,
                       const unsigned int* __restrict__ candList,
                       unsigned long long* __restrict__ rowKey) {
    int c = blockIdx.x * 256 + threadIdx.x;
    int n = min(*candCnt, CAND_CAP);
    if (c >= n) return;
    unsigned e = candList[c];
    int r = (int)(e >> 12);
    int k = (int)(e & 4095u);
    float Anp = np_sumsq256(z + (size_t)r * D);
    float C   = np_einsum_dot256(z + (size_t)r * D, cb + (size_t)k * D);
    float AB  = __fadd_rn(Anp, Bnp[k]);
    float s   = __fsub_rn(AB, __fadd_rn(C, C));
    unsigned long long key = ((unsigned long long)__float_as_uint(s) << 32) | (unsigned)k;
    atomicMin(rowKey + r, key);
}

// ---------------------------------------------------------------------------
// K6: gather out[r] = cb[idx]; idx from rowKey override (flagged) or idxArr.
__global__ void gather_kernel(const float* __restrict__ cb,
                              const int* __restrict__ idxArr,
                              const unsigned long long* __restrict__ rowKey,
                              float* __restrict__ out) {
    int r = blockIdx.x * 4 + (threadIdx.x >> 6);
    int l = threadIdx.x & 63;
    unsigned long long kv = rowKey[r];
    int ix = (kv != ~0ULL) ? (int)(kv & 0xFFFFFFFFull) : idxArr[r];
    *(float4*)(out + (size_t)r * D + l * 4) =
        *(const float4*)(cb + (size_t)ix * D + l * 4);
}

// ---------------------------------------------------------------------------
extern "C" void kernel_launch(void* const* d_in, const int* in_sizes, int n_in,
                              void* d_out, int out_size, void* d_ws, size_t ws_size,
                              hipStream_t stream) {
    const float* z  = (const float*)d_in[0];
    const float* cb = (const float*)d_in[1];
    float* out = (float*)d_out;
    const int nRows = in_sizes[0] / D;   // 65536

    char* w = (char*)d_ws;
    unsigned short* z2  = (unsigned short*)w;                         // 32 MB fp16
    unsigned short* cb2 = (unsigned short*)(w + 33554432);            // 2 MB fp16 (x4096)
    unsigned long long* rowKey = (unsigned long long*)(w + 35651584); // 512 KB
    int*   idxArr   = (int*)  (w + 36175872);                         // 256 KB
    float* rowMin   = (float*)(w + 36438016);                         // 256 KB
    int*   flagList = (int*)  (w + 36700160);                         // 256 KB
    float* Bnp      = (float*)(w + 36962304);                         // 16 KB
    unsigned int* candList = (unsigned int*)(w + 36978688);           // 512 KB
    int*   flagCnt  = (int*)  (w + 37502976);
    int*   candCnt  = flagCnt + 1;

    hipMemsetAsync(flagCnt, 0, 8, stream);
    bnp_kernel<<<NE / 256, 256, 0, stream>>>(cb, Bnp);
    tof16_kernel<<<nRows * 64 / 256, 256, 0, stream>>>(z, z2, 1.0f, nRows * 64);
    tof16_kernel<<<NE * 64 / 256, 256, 0, stream>>>(cb, cb2, 4096.0f, NE * 64);
    stageA_f16<<<nRows / MT, 256, 0, stream>>>(z2, cb2, Bnp, idxArr, rowMin,
                                               rowKey, flagCnt, flagList);
    stageB<<<dim3(nRows / BMT, NSPLIT), 256, 0, stream>>>(z, cb, Bnp, rowMin,
                                                          flagCnt, flagList,
                                                          candCnt, candList);
    stageC<<<CAND_CAP / 256, 256, 0, stream>>>(z, cb, Bnp, candCnt, candList, rowKey);
    gather_kernel<<<nRows / 4, 256, 0, stream>>>(cb, idxArr, rowKey, out);
}